// Round 1
// baseline (882.656 us; speedup 1.0000x reference)
//
#include <hip/hip_runtime.h>

typedef unsigned short u16;
typedef __attribute__((ext_vector_type(8))) short s16x8;   // 8 bf16 in 4 VGPRs
typedef __attribute__((ext_vector_type(4))) float f32x4;

#define MFMA_BF16(a,b,c) __builtin_amdgcn_mfma_f32_16x16x32_bf16((a),(b),(c),0,0,0)

__device__ __forceinline__ float b2f(u16 s){
  union { unsigned u; float f; } v; v.u = ((unsigned)s) << 16; return v.f;
}
__device__ __forceinline__ u16 f2b(float x){
  union { float f; unsigned u; } v; v.f = x;
  unsigned u = v.u;
  return (u16)((u + 0x7FFFu + ((u >> 16) & 1u)) >> 16);   // round-to-nearest-even
}
__device__ __forceinline__ u16 f2b_trunc(float x){
  union { float f; unsigned u; } v; v.f = x;
  return (u16)(v.u >> 16);                                 // truncate (softmax-safe)
}

// ---------------- all weight converts in one dispatch (f32 [K][N] -> bf16 [N][K]) ----------------
__global__ __launch_bounds__(256) void wconv_all(
    const float* __restrict__ w0, u16* __restrict__ t0,   // qkv  256x768
    const float* __restrict__ w1, u16* __restrict__ t1,   // proj 256x256
    const float* __restrict__ w2, u16* __restrict__ t2,   // fc   256x1024
    const float* __restrict__ w3, u16* __restrict__ t3)   // fc2  1024x256
{
  int bid = blockIdx.x;
  const float* w; u16* t; int K, N, base;
  if (bid < 768)        { w = w0; t = t0; K = 256;  N = 768;  base = bid; }
  else if (bid < 1024)  { w = w1; t = t1; K = 256;  N = 256;  base = bid - 768; }
  else if (bid < 2048)  { w = w2; t = t2; K = 256;  N = 1024; base = bid - 1024; }
  else                  { w = w3; t = t3; K = 1024; N = 256;  base = bid - 2048; }
  int idx = base * 256 + threadIdx.x;
  if (idx >= K * N) return;
  int k = idx / N, n = idx - k * N;
  t[(size_t)n * K + k] = f2b(w[idx]);
}

// ---------------- LayerNorm over C=256, one wave per row; f32 in -> bf16 out ----------------
__global__ __launch_bounds__(256) void ln_f32(const float* __restrict__ in,
    const float* __restrict__ gam, const float* __restrict__ bet, u16* __restrict__ out)
{
  int wv = threadIdx.x >> 6, lane = threadIdx.x & 63;
  size_t row = (size_t)blockIdx.x * 4 + wv;
  float4 u = *(const float4*)(in + row * 256 + lane * 4);
  float s  = u.x + u.y + u.z + u.w;
  float s2 = u.x*u.x + u.y*u.y + u.z*u.z + u.w*u.w;
  #pragma unroll
  for (int off = 32; off; off >>= 1){
    s  += __shfl_xor(s, off);
    s2 += __shfl_xor(s2, off);
  }
  float mean = s * (1.0f/256.0f);
  float var  = s2 * (1.0f/256.0f) - mean*mean;
  float rs   = rsqrtf(var + 1e-5f);
  int c = lane * 4;
  float4 g4 = *(const float4*)(gam + c);
  float4 b4 = *(const float4*)(bet + c);
  ushort4 o;
  o.x = f2b((u.x - mean)*rs*g4.x + b4.x);
  o.y = f2b((u.y - mean)*rs*g4.y + b4.y);
  o.z = f2b((u.z - mean)*rs*g4.z + b4.z);
  o.w = f2b((u.w - mean)*rs*g4.w + b4.w);
  *(ushort4*)(out + row * 256 + c) = o;
}

// ---------------- 128x128-tile bf16 MFMA GEMM, XCD-swizzled 1D grid ----------------
// grid.x = 512*NT. x=bid&7 (XCD), j=bid>>3: nt=j%NT, mt=(j/NT)*8+x -> same-A blocks
// back-to-back on one XCD (L2 stripe reuse).
// Epilogue is staged through LDS in 4 chunks of 32 rows x 128 cols so that the
// global stores are fully-coalesced 16B/lane (full 128B lines per wave) — the
// per-lane u16 scatter was causing ~4x HBM write amplification (measured 530MB
// written for a 134MB tensor).
// EPI 0: QKV scatter (+bias) -> o0=q (PRE-SCALED by 1/sqrt(32)), o1=k, o2=v, [bah][t][d] bf16
// EPI 2: exact GELU bf16     -> o0[row*N+col] = gelu(acc + bias)
// EPI 3: residual add f32    -> ((float*)o0)[row*N+col] = res + acc + bias
template<int EPI, int NT>
__global__ __launch_bounds__(256) void gemm128(
    const u16* __restrict__ A, const u16* __restrict__ Bt, const float* __restrict__ bias,
    const u16* __restrict__ res, void* __restrict__ o0v, u16* __restrict__ o1, u16* __restrict__ o2,
    int N, int K)
{
  // staging: A tile 8KB | B tile 8KB (16KB). epilogue chunk: 32x132 u16 (8448B)
  // or 32x133 f32 (17024B). union -> 17024B.
  __shared__ __align__(16) u16 lds[8512];
  int tid = threadIdx.x;
  int w = tid >> 6, lane = tid & 63;
  int quad = lane >> 4, c = lane & 15;
  int bid = blockIdx.x;
  int x = bid & 7, j = bid >> 3;
  int nt = j % NT, mt = (j / NT) * 8 + x;
  int wm = (w >> 1) * 64, wn = (w & 1) * 64;
  const u16* Abase = A + (size_t)mt * 128 * K;
  const u16* Bbase = Bt + (size_t)nt * 128 * K;
  f32x4 zero = {0.f, 0.f, 0.f, 0.f};
  f32x4 acc[4][4];
  #pragma unroll
  for (int mi = 0; mi < 4; mi++)
    #pragma unroll
    for (int ni = 0; ni < 4; ni++) acc[mi][ni] = zero;

  for (int k0 = 0; k0 < K; k0 += 32){
    uint4 ra[2], rb[2];
    #pragma unroll
    for (int i = 0; i < 2; i++){
      int ci = tid + i * 256;              // chunk index 0..511
      int m = ci & 127, jj = ci >> 7;
      ra[i] = *(const uint4*)(Abase + (size_t)m * K + k0 + jj * 8);
      rb[i] = *(const uint4*)(Bbase + (size_t)m * K + k0 + jj * 8);
    }
    __syncthreads();   // previous iteration's ds_reads done before overwrite
    #pragma unroll
    for (int i = 0; i < 2; i++){
      int ci = tid + i * 256;
      *(uint4*)&lds[ci * 8]        = ra[i];
      *(uint4*)&lds[4096 + ci * 8] = rb[i];
    }
    __syncthreads();
    s16x8 af[4], bfr[4];
    #pragma unroll
    for (int mi = 0; mi < 4; mi++)
      af[mi] = *(const s16x8*)&lds[(quad * 128 + wm + mi * 16 + c) * 8];
    #pragma unroll
    for (int ni = 0; ni < 4; ni++)
      bfr[ni] = *(const s16x8*)&lds[4096 + (quad * 128 + wn + ni * 16 + c) * 8];
    #pragma unroll
    for (int mi = 0; mi < 4; mi++)
      #pragma unroll
      for (int ni = 0; ni < 4; ni++)
        acc[mi][ni] = MFMA_BF16(af[mi], bfr[ni], acc[mi][ni]);
  }

  // ---------------- LDS-staged coalesced epilogue ----------------
  // chunk ch covers tile rows [ch*32, ch*32+32). Staged by the two waves with
  // wm == (ch>>1)*64 (their mi = (ch&1)*2 + {0,1}); read back by all 256 threads.
  const int LS  = 132;                 // u16 chunk row stride (pad: bank-conflict-free)
  const int LSF = 133;                 // f32 chunk row stride
  float* ldsF = (float*)lds;
  int rr  = tid >> 3;                  // readback row within chunk [0,32)
  int cc0 = (tid & 7) * 16;            // readback col base (16 elems/thread)

  #pragma unroll
  for (int ch = 0; ch < 4; ch++){
    __syncthreads();                   // K-loop ds_reads / prev readback done
    if ((w >> 1) == (ch >> 1)){
      #pragma unroll
      for (int mi2 = 0; mi2 < 2; mi2++){
        int mi = (ch & 1) * 2 + mi2;
        #pragma unroll
        for (int ni = 0; ni < 4; ni++){
          int col = wn + ni * 16 + c;                    // tile-local col
          float bv = bias[nt * 128 + col];
          #pragma unroll
          for (int r = 0; r < 4; r++){
            int cr = mi2 * 16 + quad * 4 + r;            // chunk-local row
            float vv = acc[mi][ni][r] + bv;
            if (EPI == 0){
              int gcol = nt * 128 + col;
              if ((gcol >> 8) == 0) vv *= 0.17677669529663687f;   // q pre-scale
              lds[cr * LS + col] = f2b(vv);
            } else if (EPI == 2){
              float g = 0.5f * vv * (1.0f + erff(vv * 0.70710678118654752f));
              lds[cr * LS + col] = f2b(g);
            } else {
              ldsF[cr * LSF + col] = vv;                 // residual added at readback
            }
          }
        }
      }
    }
    __syncthreads();
    int row = mt * 128 + ch * 32 + rr;                   // global output row
    if (EPI == 3){
      #pragma unroll
      for (int jj2 = 0; jj2 < 4; jj2++){
        int colL = cc0 + jj2 * 4;
        size_t gidx = (size_t)row * N + nt * 128 + colL;
        float4 vv = *(const float4*)&ldsF[rr * LSF + colL];
        ushort4 r4 = *(const ushort4*)(res + gidx);
        float4 o4;
        o4.x = vv.x + b2f(r4.x);
        o4.y = vv.y + b2f(r4.y);
        o4.z = vv.z + b2f(r4.z);
        o4.w = vv.w + b2f(r4.w);
        *(float4*)((float*)o0v + gidx) = o4;
      }
    } else {
      #pragma unroll
      for (int jj2 = 0; jj2 < 2; jj2++){
        int colL = cc0 + jj2 * 8;
        uint4 val = *(const uint4*)&lds[rr * LS + colL];
        if (EPI == 0){
          int gcol = nt * 128 + colL;
          int which = gcol >> 8, ccc = gcol & 255;
          int hh = ccc >> 5, d = ccc & 31;
          int ba = row >> 9, t = row & 511;
          size_t idx = (((size_t)(ba * 8 + hh)) * 512 + t) * 32 + d;
          u16* dst = (which == 0) ? (u16*)o0v : ((which == 1) ? o1 : o2);
          *(uint4*)(dst + idx) = val;
        } else {
          *(uint4*)((u16*)o0v + (size_t)row * N + nt * 128 + colL) = val;
        }
      }
    }
  }
}

// ---------------- fused proj GEMM + residual + LayerNorm2 -> x2n ----------------
// A=y [65536][256] bf16, Bt=projT [256][256], res=xn. Block = 64 rows x all 256 cols.
// Wave w covers cols [64w, 64w+64), 4x4 MFMA acc. x2 tile bounced via LDS (bf16),
// then 4 threads/row LN pass. x2 never hits global.
__global__ __launch_bounds__(256) void proj_ln(
    const u16* __restrict__ A, const u16* __restrict__ Bt, const float* __restrict__ bias,
    const u16* __restrict__ res, const float* __restrict__ gam, const float* __restrict__ bet,
    u16* __restrict__ x2n)
{
  __shared__ __align__(16) u16 lds[16896];           // staging (10240) / x2 tile 64x264
  int tid = threadIdx.x;
  int w = tid >> 6, lane = tid & 63;
  int quad = lane >> 4, c = lane & 15;
  int mt = blockIdx.x;                               // 64-row tiles
  int wn = w * 64;
  const u16* Abase = A + (size_t)mt * 64 * 256;
  u16* ldsA = lds;                                   // 64x32 chunks: [(j*64+m)*8]
  u16* ldsB = lds + 2048;                            // 256x32 chunks: [(j*256+n)*8]
  f32x4 zero = {0.f, 0.f, 0.f, 0.f};
  f32x4 acc[4][4];
  #pragma unroll
  for (int mi = 0; mi < 4; mi++)
    #pragma unroll
    for (int ni = 0; ni < 4; ni++) acc[mi][ni] = zero;

  for (int k0 = 0; k0 < 256; k0 += 32){
    uint4 ra = {0,0,0,0}, rb[4];
    {
      int m = tid & 63, jj = tid >> 6;               // A: 256 chunks, first 256 threads
      ra = *(const uint4*)(Abase + (size_t)m * 256 + k0 + jj * 8);
    }
    #pragma unroll
    for (int i = 0; i < 4; i++){
      int ci = tid + i * 256;                        // B: 1024 chunks
      int n = ci & 255, jj = ci >> 8;
      rb[i] = *(const uint4*)(Bt + (size_t)n * 256 + k0 + jj * 8);
    }
    __syncthreads();
    {
      int m = tid & 63, jj = tid >> 6;
      *(uint4*)&ldsA[(jj * 64 + m) * 8] = ra;
    }
    #pragma unroll
    for (int i = 0; i < 4; i++){
      int ci = tid + i * 256;
      int n = ci & 255, jj = ci >> 8;
      *(uint4*)&ldsB[(jj * 256 + n) * 8] = rb[i];
    }
    __syncthreads();
    s16x8 af[4], bfr[4];
    #pragma unroll
    for (int mi = 0; mi < 4; mi++)
      af[mi] = *(const s16x8*)&ldsA[(quad * 64 + mi * 16 + c) * 8];
    #pragma unroll
    for (int ni = 0; ni < 4; ni++)
      bfr[ni] = *(const s16x8*)&ldsB[(quad * 256 + wn + ni * 16 + c) * 8];
    #pragma unroll
    for (int mi = 0; mi < 4; mi++)
      #pragma unroll
      for (int ni = 0; ni < 4; ni++)
        acc[mi][ni] = MFMA_BF16(af[mi], bfr[ni], acc[mi][ni]);
    __syncthreads();                                 // frags consumed before restage
  }

  // epilogue: x2 = y@W + b + xn -> LDS tile [64][264] bf16
  #pragma unroll
  for (int ni = 0; ni < 4; ni++){
    int col = wn + ni * 16 + c;
    float bv = bias[col];
    #pragma unroll
    for (int mi = 0; mi < 4; mi++){
      #pragma unroll
      for (int r = 0; r < 4; r++){
        int rowL = mi * 16 + quad * 4 + r;
        size_t gidx = ((size_t)mt * 64 + rowL) * 256 + col;
        lds[rowL * 264 + col] = f2b(acc[mi][ni][r] + bv + b2f(res[gidx]));
      }
    }
  }
  __syncthreads();

  // LN pass: 4 threads per row, each owns 64 cols
  int rowL = tid >> 2, part = (tid & 3) * 64;
  float s = 0.f, s2 = 0.f;
  #pragma unroll
  for (int i = 0; i < 16; i++){
    ushort4 u = *(const ushort4*)&lds[rowL * 264 + part + i * 4];
    float v0 = b2f(u.x), v1 = b2f(u.y), v2 = b2f(u.z), v3 = b2f(u.w);
    s  += v0 + v1 + v2 + v3;
    s2 += v0*v0 + v1*v1 + v2*v2 + v3*v3;
  }
  s  += __shfl_xor(s, 1);  s  += __shfl_xor(s, 2);
  s2 += __shfl_xor(s2, 1); s2 += __shfl_xor(s2, 2);
  float mean = s * (1.0f/256.0f);
  float var  = s2 * (1.0f/256.0f) - mean*mean;
  float rs   = rsqrtf(var + 1e-5f);
  size_t orow = ((size_t)mt * 64 + rowL) * 256;
  #pragma unroll
  for (int i = 0; i < 16; i++){
    int col = part + i * 4;
    ushort4 u = *(const ushort4*)&lds[rowL * 264 + col];
    float4 g4 = *(const float4*)(gam + col);
    float4 b4 = *(const float4*)(bet + col);
    ushort4 o;
    o.x = f2b((b2f(u.x) - mean)*rs*g4.x + b4.x);
    o.y = f2b((b2f(u.y) - mean)*rs*g4.y + b4.y);
    o.z = f2b((b2f(u.z) - mean)*rs*g4.z + b4.z);
    o.w = f2b((b2f(u.w) - mean)*rs*g4.w + b4.w);
    *(ushort4*)(x2n + orow + col) = o;
  }
}

// ---------------- flash attention, no-max softmax; XCD-swizzled 1D grid ----------------
// q (pre-scaled), k, v: [bah][t][32] bf16; y: [ba][t][256] bf16.
// grid.x = 4096: x=bid&7, j=bid>>3: qt=j&3, bah=(j>>2)*8+x -> a bah's 4 q-tiles
// back-to-back on one XCD (K/V L2 reuse).
__global__ __launch_bounds__(256) void attn_kernel(const u16* __restrict__ q,
    const u16* __restrict__ k, const u16* __restrict__ v, u16* __restrict__ y)
{
  __shared__ __align__(16) u16 ldsK[32 * 36];    // [s][d], row stride 36
  __shared__ __align__(16) u16 ldsV[32 * 36];    // [d][s], row stride 36
  __shared__ __align__(16) u16 ldsp[4][16 * 36]; // per-wave P [prow][s], stride 36
  int tid = threadIdx.x;
  int w = tid >> 6, lane = tid & 63;
  int quad = lane >> 4, c = lane & 15;
  int bid = blockIdx.x;
  int x = bid & 7, j = bid >> 3;
  int qt = j & 3, bah = (j >> 2) * 8 + x;
  int q0 = qt * 128 + w * 32;
  const u16* qb = q + (size_t)bah * 16384;
  const u16* kb = k + (size_t)bah * 16384;
  const u16* vb = v + (size_t)bah * 16384;
  int krow = tid >> 3, kcol = (tid & 7) * 4;     // K staging: uint2 per thread
  int vd = tid & 31,  vs = (tid >> 5) * 4;       // V staging: 4 strided u16 -> b64

  s16x8 qf0 = *(const s16x8*)(qb + (q0 + c) * 32 + quad * 8);
  s16x8 qf1 = *(const s16x8*)(qb + (q0 + 16 + c) * 32 + quad * 8);
  float l0[4] = {0.f,0.f,0.f,0.f}, l1[4] = {0.f,0.f,0.f,0.f};
  f32x4 o00 = {0,0,0,0}, o01 = {0,0,0,0}, o10 = {0,0,0,0}, o11 = {0,0,0,0};
  f32x4 zero = {0,0,0,0};

  for (int s0 = 0; s0 < 512; s0 += 32){
    uint2 kr = *(const uint2*)(kb + (s0 + krow) * 32 + kcol);
    short4 vr;
    vr.x = (short)vb[(s0 + vs)     * 32 + vd];
    vr.y = (short)vb[(s0 + vs + 1) * 32 + vd];
    vr.z = (short)vb[(s0 + vs + 2) * 32 + vd];
    vr.w = (short)vb[(s0 + vs + 3) * 32 + vd];
    __syncthreads();
    *(uint2*)&ldsK[krow * 36 + kcol] = kr;
    *(short4*)&ldsV[vd * 36 + vs]   = vr;
    __syncthreads();

    s16x8 kf0 = *(const s16x8*)&ldsK[c * 36 + quad * 8];
    s16x8 kf1 = *(const s16x8*)&ldsK[(16 + c) * 36 + quad * 8];
    s16x8 vf0 = *(const s16x8*)&ldsV[c * 36 + quad * 8];
    s16x8 vf1 = *(const s16x8*)&ldsV[(16 + c) * 36 + quad * 8];

    f32x4 S0 = MFMA_BF16(qf0, kf0, zero);
    f32x4 S1 = MFMA_BF16(qf0, kf1, zero);
    #pragma unroll
    for (int r = 0; r < 4; r++){
      float p0 = __expf(S0[r]), p1 = __expf(S1[r]);
      l0[r] += p0 + p1;
      int prow = quad * 4 + r;
      ldsp[w][prow * 36 + c]      = f2b_trunc(p0);
      ldsp[w][prow * 36 + 16 + c] = f2b_trunc(p1);
    }
    s16x8 pf = *(const s16x8*)&ldsp[w][c * 36 + quad * 8];
    o00 = MFMA_BF16(pf, vf0, o00);
    o01 = MFMA_BF16(pf, vf1, o01);

    S0 = MFMA_BF16(qf1, kf0, zero);
    S1 = MFMA_BF16(qf1, kf1, zero);
    #pragma unroll
    for (int r = 0; r < 4; r++){
      float p0 = __expf(S0[r]), p1 = __expf(S1[r]);
      l1[r] += p0 + p1;
      int prow = quad * 4 + r;
      ldsp[w][prow * 36 + c]      = f2b_trunc(p0);
      ldsp[w][prow * 36 + 16 + c] = f2b_trunc(p1);
    }
    pf = *(const s16x8*)&ldsp[w][c * 36 + quad * 8];
    o10 = MFMA_BF16(pf, vf0, o10);
    o11 = MFMA_BF16(pf, vf1, o11);
  }

  #pragma unroll
  for (int r = 0; r < 4; r++){
    #pragma unroll
    for (int off = 8; off; off >>= 1){
      l0[r] += __shfl_xor(l0[r], off);
      l1[r] += __shfl_xor(l1[r], off);
    }
  }

  int ba = bah >> 3, hh = bah & 7;
  #pragma unroll
  for (int r = 0; r < 4; r++){
    int t0 = q0 + quad * 4 + r;
    float inv0 = 1.0f / l0[r], inv1 = 1.0f / l1[r];
    size_t base0 = ((size_t)(ba * 512 + t0)) * 256 + hh * 32;
    size_t base1 = base0 + 16 * 256;
    y[base0 + c]      = f2b(o00[r] * inv0);
    y[base0 + 16 + c] = f2b(o01[r] * inv0);
    y[base1 + c]      = f2b(o10[r] * inv1);
    y[base1 + 16 + c] = f2b(o11[r] * inv1);
  }
}

// ---------------- launch ----------------
extern "C" void kernel_launch(void* const* d_in, const int* in_sizes, int n_in,
                              void* d_out, int out_size, void* d_ws, size_t ws_size,
                              hipStream_t stream)
{
  const float* x      = (const float*)d_in[0];
  const float* ln1_w  = (const float*)d_in[1];
  const float* ln1_b  = (const float*)d_in[2];
  const float* qkv_w  = (const float*)d_in[3];
  const float* qkv_b  = (const float*)d_in[4];
  const float* proj_w = (const float*)d_in[5];
  const float* proj_b = (const float*)d_in[6];
  const float* ln2_w  = (const float*)d_in[7];
  const float* ln2_b  = (const float*)d_in[8];
  const float* fc_w   = (const float*)d_in[9];
  const float* fc_b   = (const float*)d_in[10];
  const float* fc2_w  = (const float*)d_in[11];
  const float* fc2_b  = (const float*)d_in[12];
  float* out = (float*)d_out;
  char* ws = (char*)d_ws;

  // ws layout (bytes) — compacted to cut poison-touch:
  // [0,32M) xn | [32M,166M) q|k|v|y (h overlaps) | [166M,200M) x2n | [200M,~201M) weights
  u16* xn   = (u16*)ws;
  u16* qb   = (u16*)(ws + (size_t)33554432);
  u16* kb   = qb + 16777216;
  u16* vb   = kb + 16777216;
  u16* yb   = vb + 16777216;
  u16* hb   = qb;                                   // overlap: q/k/v/y dead by FC1
  u16* x2n  = (u16*)(ws + (size_t)173015040);
  u16* wqkvT  = (u16*)(ws + (size_t)206569472);
  u16* wprojT = wqkvT + 196608;
  u16* wfcT   = wprojT + 65536;
  u16* wfc2T  = wfcT + 262144;

  wconv_all<<<3072, 256, 0, stream>>>(qkv_w, wqkvT, proj_w, wprojT, fc_w, wfcT, fc2_w, wfc2T);

  ln_f32<<<16384, 256, 0, stream>>>(x, ln1_w, ln1_b, xn);
  gemm128<0,6><<<3072, 256, 0, stream>>>(xn, wqkvT, qkv_b, nullptr, qb, kb, vb, 768, 256);
  attn_kernel<<<4096, 256, 0, stream>>>(qb, kb, vb, yb);
  proj_ln<<<1024, 256, 0, stream>>>(yb, wprojT, proj_b, xn, ln2_w, ln2_b, x2n);
  gemm128<2,8><<<4096, 256, 0, stream>>>(x2n, wfcT, fc_b, nullptr, hb, nullptr, nullptr, 1024, 256);
  gemm128<3,2><<<1024, 256, 0, stream>>>(hb, wfc2T, fc2_b, x2n, out, nullptr, nullptr, 256, 1024);
}

// Round 2
// 586.670 us; speedup vs baseline: 1.5045x; 1.5045x over previous
//
#include <hip/hip_runtime.h>

typedef unsigned short u16;
typedef __attribute__((ext_vector_type(8))) short s16x8;   // 8 bf16 in 4 VGPRs
typedef __attribute__((ext_vector_type(4))) float f32x4;

#define MFMA_BF16(a,b,c) __builtin_amdgcn_mfma_f32_16x16x32_bf16((a),(b),(c),0,0,0)

// async global->LDS, 16B per lane. LDS dest is wave-uniform base + lane*16;
// our staging layouts are lane-linear so per-lane pointer == base + lane*16.
#define GLL(gp, lp) __builtin_amdgcn_global_load_lds( \
    (const __attribute__((address_space(1))) void*)(gp), \
    (__attribute__((address_space(3))) void*)(lp), 16, 0, 0)

// counted-vmcnt barrier: wait for all but the newest N vmem ops, then s_barrier.
// asm memory clobber + sched_barrier(0) fence per guide rule #18.
#define PIPE_WAIT_BAR(N) do { \
  asm volatile("s_waitcnt vmcnt(" #N ")" ::: "memory"); \
  __builtin_amdgcn_sched_barrier(0); \
  __builtin_amdgcn_s_barrier(); \
  __builtin_amdgcn_sched_barrier(0); \
} while (0)

#define PIPE_BAR() do { \
  asm volatile("" ::: "memory"); \
  __builtin_amdgcn_sched_barrier(0); \
  __builtin_amdgcn_s_barrier(); \
  __builtin_amdgcn_sched_barrier(0); \
} while (0)

__device__ __forceinline__ float b2f(u16 s){
  union { unsigned u; float f; } v; v.u = ((unsigned)s) << 16; return v.f;
}
__device__ __forceinline__ u16 f2b(float x){
  union { float f; unsigned u; } v; v.f = x;
  unsigned u = v.u;
  return (u16)((u + 0x7FFFu + ((u >> 16) & 1u)) >> 16);   // round-to-nearest-even
}
__device__ __forceinline__ u16 f2b_trunc(float x){
  union { float f; unsigned u; } v; v.f = x;
  return (u16)(v.u >> 16);                                 // truncate (softmax-safe)
}

// ---------------- all weight converts in one dispatch (f32 [K][N] -> bf16 [N][K]) ----------------
__global__ __launch_bounds__(256) void wconv_all(
    const float* __restrict__ w0, u16* __restrict__ t0,   // qkv  256x768
    const float* __restrict__ w1, u16* __restrict__ t1,   // proj 256x256
    const float* __restrict__ w2, u16* __restrict__ t2,   // fc   256x1024
    const float* __restrict__ w3, u16* __restrict__ t3)   // fc2  1024x256
{
  int bid = blockIdx.x;
  const float* w; u16* t; int K, N, base;
  if (bid < 768)        { w = w0; t = t0; K = 256;  N = 768;  base = bid; }
  else if (bid < 1024)  { w = w1; t = t1; K = 256;  N = 256;  base = bid - 768; }
  else if (bid < 2048)  { w = w2; t = t2; K = 256;  N = 1024; base = bid - 1024; }
  else                  { w = w3; t = t3; K = 1024; N = 256;  base = bid - 2048; }
  int idx = base * 256 + threadIdx.x;
  if (idx >= K * N) return;
  int k = idx / N, n = idx - k * N;
  t[(size_t)n * K + k] = f2b(w[idx]);
}

// ---------------- LayerNorm over C=256, one wave per row; f32 in -> bf16 out ----------------
__global__ __launch_bounds__(256) void ln_f32(const float* __restrict__ in,
    const float* __restrict__ gam, const float* __restrict__ bet, u16* __restrict__ out)
{
  int wv = threadIdx.x >> 6, lane = threadIdx.x & 63;
  size_t row = (size_t)blockIdx.x * 4 + wv;
  float4 u = *(const float4*)(in + row * 256 + lane * 4);
  float s  = u.x + u.y + u.z + u.w;
  float s2 = u.x*u.x + u.y*u.y + u.z*u.z + u.w*u.w;
  #pragma unroll
  for (int off = 32; off; off >>= 1){
    s  += __shfl_xor(s, off);
    s2 += __shfl_xor(s2, off);
  }
  float mean = s * (1.0f/256.0f);
  float var  = s2 * (1.0f/256.0f) - mean*mean;
  float rs   = rsqrtf(var + 1e-5f);
  int c = lane * 4;
  float4 g4 = *(const float4*)(gam + c);
  float4 b4 = *(const float4*)(bet + c);
  ushort4 o;
  o.x = f2b((u.x - mean)*rs*g4.x + b4.x);
  o.y = f2b((u.y - mean)*rs*g4.y + b4.y);
  o.z = f2b((u.z - mean)*rs*g4.z + b4.z);
  o.w = f2b((u.w - mean)*rs*g4.w + b4.w);
  *(ushort4*)(out + row * 256 + c) = o;
}

// ---------------- 128x128-tile bf16 MFMA GEMM, XCD-swizzled 1D grid ----------------
// K-loop is a 2-phase pipeline: global_load_lds (16B) into double-buffered LDS,
// counted vmcnt(4) (never 0 in-loop) so the next tile's loads stay in flight
// across the barrier while MFMA consumes the current tile.
// Epilogue: LDS-staged chunks; readback stores full contiguous 128B lines
// (colL = c7*8 + jj2*64) to kill partial-line write amplification.
// EPI 0: QKV scatter (+bias) -> o0=q (PRE-SCALED by 1/sqrt(32)), o1=k, o2=v, [bah][t][d] bf16
// EPI 2: exact GELU bf16     -> o0[row*N+col] = gelu(acc + bias)
// EPI 3: residual add f32    -> ((float*)o0)[row*N+col] = res + acc + bias
template<int EPI, int NT>
__global__ __launch_bounds__(256) void gemm128(
    const u16* __restrict__ A, const u16* __restrict__ Bt, const float* __restrict__ bias,
    const u16* __restrict__ res, void* __restrict__ o0v, u16* __restrict__ o1, u16* __restrict__ o2,
    int N, int K)
{
  // double buffer: buf b at lds + b*8192 u16 (A 4096 | B 4096). 32KB total.
  // epilogue chunk reuses this space (max 17024B needed).
  __shared__ __align__(16) u16 lds[16384];
  int tid = threadIdx.x;
  int w = tid >> 6, lane = tid & 63;
  int quad = lane >> 4, c = lane & 15;
  int bid = blockIdx.x;
  int x = bid & 7, j = bid >> 3;
  int nt = j % NT, mt = (j / NT) * 8 + x;
  int wm = (w >> 1) * 64, wn = (w & 1) * 64;
  const u16* Abase = A + (size_t)mt * 128 * K;
  const u16* Bbase = Bt + (size_t)nt * 128 * K;
  int m0 = tid & 127, jj0 = tid >> 7;   // chunk ci=tid -> (m0,jj0); ci=tid+256 -> (m0,jj0+2)
  f32x4 zero = {0.f, 0.f, 0.f, 0.f};
  f32x4 acc[4][4];
  #pragma unroll
  for (int mi = 0; mi < 4; mi++)
    #pragma unroll
    for (int ni = 0; ni < 4; ni++) acc[mi][ni] = zero;

  auto stage = [&](int buf, int k0){
    u16* base = &lds[buf * 8192];
    GLL(Abase + (size_t)m0 * K + k0 + jj0 * 8,       &base[tid * 8]);
    GLL(Abase + (size_t)m0 * K + k0 + (jj0 + 2) * 8, &base[2048 + tid * 8]);
    GLL(Bbase + (size_t)m0 * K + k0 + jj0 * 8,       &base[4096 + tid * 8]);
    GLL(Bbase + (size_t)m0 * K + k0 + (jj0 + 2) * 8, &base[6144 + tid * 8]);
  };
  auto compute = [&](int cb){
    const u16* Lb = &lds[cb * 8192];
    s16x8 af[4], bfr[4];
    #pragma unroll
    for (int mi = 0; mi < 4; mi++)
      af[mi] = *(const s16x8*)&Lb[(quad * 128 + wm + mi * 16 + c) * 8];
    #pragma unroll
    for (int ni = 0; ni < 4; ni++)
      bfr[ni] = *(const s16x8*)&Lb[4096 + (quad * 128 + wn + ni * 16 + c) * 8];
    #pragma unroll
    for (int mi = 0; mi < 4; mi++)
      #pragma unroll
      for (int ni = 0; ni < 4; ni++)
        acc[mi][ni] = MFMA_BF16(af[mi], bfr[ni], acc[mi][ni]);
  };

  stage(0, 0);
  int cur = 0;
  for (int k0 = 32; k0 < K; k0 += 32){
    stage(cur ^ 1, k0);        // 4 loads in flight across the barrier
    PIPE_WAIT_BAR(4);          // previous stage's 4 loads complete (all waves)
    compute(cur);
    PIPE_BAR();                // all waves done reading buf[cur] before overwrite
    cur ^= 1;
  }
  PIPE_WAIT_BAR(0);
  compute(cur);

  // ---------------- LDS-staged coalesced epilogue ----------------
  // chunk ch covers tile rows [ch*32, ch*32+32). Staged by the two waves with
  // wm == (ch>>1)*64; read back by all 256 threads as full 128B lines.
  const int LS  = 132;                 // u16 chunk row stride
  const int LSF = 133;                 // f32 chunk row stride
  float* ldsF = (float*)lds;
  int rr = tid >> 3;                   // readback row within chunk [0,32)
  int c7 = tid & 7;

  #pragma unroll
  for (int ch = 0; ch < 4; ch++){
    __syncthreads();                   // prior reads of lds done
    if ((w >> 1) == (ch >> 1)){
      #pragma unroll
      for (int mi2 = 0; mi2 < 2; mi2++){
        int mi = (ch & 1) * 2 + mi2;
        #pragma unroll
        for (int ni = 0; ni < 4; ni++){
          int col = wn + ni * 16 + c;                    // tile-local col
          float bv = bias[nt * 128 + col];
          #pragma unroll
          for (int r = 0; r < 4; r++){
            int cr = mi2 * 16 + quad * 4 + r;            // chunk-local row
            float vv = acc[mi][ni][r] + bv;
            if (EPI == 0){
              int gcol = nt * 128 + col;
              if ((gcol >> 8) == 0) vv *= 0.17677669529663687f;   // q pre-scale
              lds[cr * LS + col] = f2b(vv);
            } else if (EPI == 2){
              float g = 0.5f * vv * (1.0f + erff(vv * 0.70710678118654752f));
              lds[cr * LS + col] = f2b(g);
            } else {
              ldsF[cr * LSF + col] = vv;                 // residual added at readback
            }
          }
        }
      }
    }
    __syncthreads();
    int row = mt * 128 + ch * 32 + rr;                   // global output row
    if (EPI == 3){
      #pragma unroll
      for (int jj2 = 0; jj2 < 4; jj2++){
        int colL = c7 * 4 + jj2 * 32;                    // 8 lanes x 16B contiguous
        size_t gidx = (size_t)row * N + nt * 128 + colL;
        float4 vv = *(const float4*)&ldsF[rr * LSF + colL];
        ushort4 r4 = *(const ushort4*)(res + gidx);
        float4 o4;
        o4.x = vv.x + b2f(r4.x);
        o4.y = vv.y + b2f(r4.y);
        o4.z = vv.z + b2f(r4.z);
        o4.w = vv.w + b2f(r4.w);
        *(float4*)((float*)o0v + gidx) = o4;
      }
    } else {
      #pragma unroll
      for (int jj2 = 0; jj2 < 2; jj2++){
        int colL = c7 * 8 + jj2 * 64;                    // 8 lanes x 16B contiguous
        uint4 val = *(const uint4*)&lds[rr * LS + colL];
        if (EPI == 0){
          int gcol = nt * 128 + colL;
          int which = gcol >> 8, ccc = gcol & 255;
          int hh = ccc >> 5, d = ccc & 31;
          int ba = row >> 9, t = row & 511;
          size_t idx = (((size_t)(ba * 8 + hh)) * 512 + t) * 32 + d;
          u16* dst = (which == 0) ? (u16*)o0v : ((which == 1) ? o1 : o2);
          *(uint4*)(dst + idx) = val;
        } else {
          *(uint4*)((u16*)o0v + (size_t)row * N + nt * 128 + colL) = val;
        }
      }
    }
  }
}

// ---------------- fused proj GEMM + residual + LayerNorm2 -> x2n ----------------
// Same 2-phase global_load_lds pipeline (5 loads/stage -> vmcnt(5)).
// A=y [65536][256] bf16, Bt=projT [256][256], res=xn. Block = 64 rows x all 256 cols.
__global__ __launch_bounds__(256) void proj_ln(
    const u16* __restrict__ A, const u16* __restrict__ Bt, const float* __restrict__ bias,
    const u16* __restrict__ res, const float* __restrict__ gam, const float* __restrict__ bet,
    u16* __restrict__ x2n)
{
  // double buffer: buf b at lds + b*10240 u16 (A 2048 | B 8192). 40KB total.
  // epilogue x2 tile 64x264 u16 (33792B) reuses this space.
  __shared__ __align__(16) u16 lds[20480];
  int tid = threadIdx.x;
  int w = tid >> 6, lane = tid & 63;
  int quad = lane >> 4, c = lane & 15;
  int mt = blockIdx.x;                               // 64-row tiles
  int wn = w * 64;
  const u16* Abase = A + (size_t)mt * 64 * 256;
  int an = tid & 63, aj = tid >> 6;
  f32x4 zero = {0.f, 0.f, 0.f, 0.f};
  f32x4 acc[4][4];
  #pragma unroll
  for (int mi = 0; mi < 4; mi++)
    #pragma unroll
    for (int ni = 0; ni < 4; ni++) acc[mi][ni] = zero;

  auto stage = [&](int buf, int k0){
    u16* base = &lds[buf * 10240];
    GLL(Abase + (size_t)an * 256 + k0 + aj * 8, &base[tid * 8]);
    #pragma unroll
    for (int i = 0; i < 4; i++){
      int ci = tid + i * 256;
      int n = ci & 255, jjb = ci >> 8;
      GLL(Bt + (size_t)n * 256 + k0 + jjb * 8, &base[2048 + ci * 8]);
    }
  };
  auto compute = [&](int cb){
    const u16* base = &lds[cb * 10240];
    s16x8 af[4], bfr[4];
    #pragma unroll
    for (int mi = 0; mi < 4; mi++)
      af[mi] = *(const s16x8*)&base[(quad * 64 + mi * 16 + c) * 8];
    #pragma unroll
    for (int ni = 0; ni < 4; ni++)
      bfr[ni] = *(const s16x8*)&base[2048 + (quad * 256 + wn + ni * 16 + c) * 8];
    #pragma unroll
    for (int mi = 0; mi < 4; mi++)
      #pragma unroll
      for (int ni = 0; ni < 4; ni++)
        acc[mi][ni] = MFMA_BF16(af[mi], bfr[ni], acc[mi][ni]);
  };

  stage(0, 0);
  int cur = 0;
  for (int k0 = 32; k0 < 256; k0 += 32){
    stage(cur ^ 1, k0);
    PIPE_WAIT_BAR(5);
    compute(cur);
    PIPE_BAR();
    cur ^= 1;
  }
  PIPE_WAIT_BAR(0);
  compute(cur);
  __syncthreads();

  // epilogue: x2 = y@W + b + xn -> LDS tile [64][264] bf16
  #pragma unroll
  for (int ni = 0; ni < 4; ni++){
    int col = wn + ni * 16 + c;
    float bv = bias[col];
    #pragma unroll
    for (int mi = 0; mi < 4; mi++){
      #pragma unroll
      for (int r = 0; r < 4; r++){
        int rowL = mi * 16 + quad * 4 + r;
        size_t gidx = ((size_t)mt * 64 + rowL) * 256 + col;
        lds[rowL * 264 + col] = f2b(acc[mi][ni][r] + bv + b2f(res[gidx]));
      }
    }
  }
  __syncthreads();

  // LN pass: 4 threads per row, each owns 64 cols
  int rowL = tid >> 2, part = (tid & 3) * 64;
  float s = 0.f, s2 = 0.f;
  #pragma unroll
  for (int i = 0; i < 16; i++){
    ushort4 u = *(const ushort4*)&lds[rowL * 264 + part + i * 4];
    float v0 = b2f(u.x), v1 = b2f(u.y), v2 = b2f(u.z), v3 = b2f(u.w);
    s  += v0 + v1 + v2 + v3;
    s2 += v0*v0 + v1*v1 + v2*v2 + v3*v3;
  }
  s  += __shfl_xor(s, 1);  s  += __shfl_xor(s, 2);
  s2 += __shfl_xor(s2, 1); s2 += __shfl_xor(s2, 2);
  float mean = s * (1.0f/256.0f);
  float var  = s2 * (1.0f/256.0f) - mean*mean;
  float rs   = rsqrtf(var + 1e-5f);
  size_t orow = ((size_t)mt * 64 + rowL) * 256;
  #pragma unroll
  for (int i = 0; i < 16; i++){
    int col = part + i * 4;
    ushort4 u = *(const ushort4*)&lds[rowL * 264 + col];
    float4 g4 = *(const float4*)(gam + col);
    float4 b4 = *(const float4*)(bet + col);
    ushort4 o;
    o.x = f2b((b2f(u.x) - mean)*rs*g4.x + b4.x);
    o.y = f2b((b2f(u.y) - mean)*rs*g4.y + b4.y);
    o.z = f2b((b2f(u.z) - mean)*rs*g4.z + b4.z);
    o.w = f2b((b2f(u.w) - mean)*rs*g4.w + b4.w);
    *(ushort4*)(x2n + orow + col) = o;
  }
}

// ---------------- flash attention, no-max softmax; XCD-swizzled 1D grid ----------------
// q (pre-scaled), k, v: [bah][t][32] bf16; y: [ba][t][256] bf16.
// grid.x = 4096: x=bid&7, j=bid>>3: qt=j&3, bah=(j>>2)*8+x -> a bah's 4 q-tiles
// back-to-back on one XCD (K/V L2 reuse).
__global__ __launch_bounds__(256) void attn_kernel(const u16* __restrict__ q,
    const u16* __restrict__ k, const u16* __restrict__ v, u16* __restrict__ y)
{
  __shared__ __align__(16) u16 ldsK[32 * 36];    // [s][d], row stride 36
  __shared__ __align__(16) u16 ldsV[32 * 36];    // [d][s], row stride 36
  __shared__ __align__(16) u16 ldsp[4][16 * 36]; // per-wave P [prow][s], stride 36
  int tid = threadIdx.x;
  int w = tid >> 6, lane = tid & 63;
  int quad = lane >> 4, c = lane & 15;
  int bid = blockIdx.x;
  int x = bid & 7, j = bid >> 3;
  int qt = j & 3, bah = (j >> 2) * 8 + x;
  int q0 = qt * 128 + w * 32;
  const u16* qb = q + (size_t)bah * 16384;
  const u16* kb = k + (size_t)bah * 16384;
  const u16* vb = v + (size_t)bah * 16384;
  int krow = tid >> 3, kcol = (tid & 7) * 4;     // K staging: uint2 per thread
  int vd = tid & 31,  vs = (tid >> 5) * 4;       // V staging: 4 strided u16 -> b64

  s16x8 qf0 = *(const s16x8*)(qb + (q0 + c) * 32 + quad * 8);
  s16x8 qf1 = *(const s16x8*)(qb + (q0 + 16 + c) * 32 + quad * 8);
  float l0[4] = {0.f,0.f,0.f,0.f}, l1[4] = {0.f,0.f,0.f,0.f};
  f32x4 o00 = {0,0,0,0}, o01 = {0,0,0,0}, o10 = {0,0,0,0}, o11 = {0,0,0,0};
  f32x4 zero = {0,0,0,0};

  for (int s0 = 0; s0 < 512; s0 += 32){
    uint2 kr = *(const uint2*)(kb + (s0 + krow) * 32 + kcol);
    short4 vr;
    vr.x = (short)vb[(s0 + vs)     * 32 + vd];
    vr.y = (short)vb[(s0 + vs + 1) * 32 + vd];
    vr.z = (short)vb[(s0 + vs + 2) * 32 + vd];
    vr.w = (short)vb[(s0 + vs + 3) * 32 + vd];
    __syncthreads();
    *(uint2*)&ldsK[krow * 36 + kcol] = kr;
    *(short4*)&ldsV[vd * 36 + vs]   = vr;
    __syncthreads();

    s16x8 kf0 = *(const s16x8*)&ldsK[c * 36 + quad * 8];
    s16x8 kf1 = *(const s16x8*)&ldsK[(16 + c) * 36 + quad * 8];
    s16x8 vf0 = *(const s16x8*)&ldsV[c * 36 + quad * 8];
    s16x8 vf1 = *(const s16x8*)&ldsV[(16 + c) * 36 + quad * 8];

    f32x4 S0 = MFMA_BF16(qf0, kf0, zero);
    f32x4 S1 = MFMA_BF16(qf0, kf1, zero);
    #pragma unroll
    for (int r = 0; r < 4; r++){
      float p0 = __expf(S0[r]), p1 = __expf(S1[r]);
      l0[r] += p0 + p1;
      int prow = quad * 4 + r;
      ldsp[w][prow * 36 + c]      = f2b_trunc(p0);
      ldsp[w][prow * 36 + 16 + c] = f2b_trunc(p1);
    }
    s16x8 pf = *(const s16x8*)&ldsp[w][c * 36 + quad * 8];
    o00 = MFMA_BF16(pf, vf0, o00);
    o01 = MFMA_BF16(pf, vf1, o01);

    S0 = MFMA_BF16(qf1, kf0, zero);
    S1 = MFMA_BF16(qf1, kf1, zero);
    #pragma unroll
    for (int r = 0; r < 4; r++){
      float p0 = __expf(S0[r]), p1 = __expf(S1[r]);
      l1[r] += p0 + p1;
      int prow = quad * 4 + r;
      ldsp[w][prow * 36 + c]      = f2b_trunc(p0);
      ldsp[w][prow * 36 + 16 + c] = f2b_trunc(p1);
    }
    pf = *(const s16x8*)&ldsp[w][c * 36 + quad * 8];
    o10 = MFMA_BF16(pf, vf0, o10);
    o11 = MFMA_BF16(pf, vf1, o11);
  }

  #pragma unroll
  for (int r = 0; r < 4; r++){
    #pragma unroll
    for (int off = 8; off; off >>= 1){
      l0[r] += __shfl_xor(l0[r], off);
      l1[r] += __shfl_xor(l1[r], off);
    }
  }

  int ba = bah >> 3, hh = bah & 7;
  #pragma unroll
  for (int r = 0; r < 4; r++){
    int t0 = q0 + quad * 4 + r;
    float inv0 = 1.0f / l0[r], inv1 = 1.0f / l1[r];
    size_t base0 = ((size_t)(ba * 512 + t0)) * 256 + hh * 32;
    size_t base1 = base0 + 16 * 256;
    y[base0 + c]      = f2b(o00[r] * inv0);
    y[base0 + 16 + c] = f2b(o01[r] * inv0);
    y[base1 + c]      = f2b(o10[r] * inv1);
    y[base1 + 16 + c] = f2b(o11[r] * inv1);
  }
}

// ---------------- launch ----------------
extern "C" void kernel_launch(void* const* d_in, const int* in_sizes, int n_in,
                              void* d_out, int out_size, void* d_ws, size_t ws_size,
                              hipStream_t stream)
{
  const float* x      = (const float*)d_in[0];
  const float* ln1_w  = (const float*)d_in[1];
  const float* ln1_b  = (const float*)d_in[2];
  const float* qkv_w  = (const float*)d_in[3];
  const float* qkv_b  = (const float*)d_in[4];
  const float* proj_w = (const float*)d_in[5];
  const float* proj_b = (const float*)d_in[6];
  const float* ln2_w  = (const float*)d_in[7];
  const float* ln2_b  = (const float*)d_in[8];
  const float* fc_w   = (const float*)d_in[9];
  const float* fc_b   = (const float*)d_in[10];
  const float* fc2_w  = (const float*)d_in[11];
  const float* fc2_b  = (const float*)d_in[12];
  float* out = (float*)d_out;
  char* ws = (char*)d_ws;

  // ws layout (bytes) — compacted to cut poison-touch:
  // [0,32M) xn | [32M,166M) q|k|v|y (h overlaps) | [166M,200M) x2n | [200M,~201M) weights
  u16* xn   = (u16*)ws;
  u16* qb   = (u16*)(ws + (size_t)33554432);
  u16* kb   = qb + 16777216;
  u16* vb   = kb + 16777216;
  u16* yb   = vb + 16777216;
  u16* hb   = qb;                                   // overlap: q/k/v/y dead by FC1
  u16* x2n  = (u16*)(ws + (size_t)173015040);
  u16* wqkvT  = (u16*)(ws + (size_t)206569472);
  u16* wprojT = wqkvT + 196608;
  u16* wfcT   = wprojT + 65536;
  u16* wfc2T  = wfcT + 262144;

  wconv_all<<<3072, 256, 0, stream>>>(qkv_w, wqkvT, proj_w, wprojT, fc_w, wfcT, fc2_w, wfc2T);

  ln_f32<<<16384, 256, 0, stream>>>(x, ln1_w, ln1_b, xn);
  gemm128<0,6><<<3072, 256, 0, stream>>>(xn, wqkvT, qkv_b, nullptr, qb, kb, vb, 768, 256);
  attn_kernel<<<4096, 256, 0, stream>>>(qb, kb, vb, yb);
  proj_ln<<<1024, 256, 0, stream>>>(yb, wprojT, proj_b, xn, ln2_w, ln2_b, x2n);
  gemm128<2,8><<<4096, 256, 0, stream>>>(x2n, wfcT, fc_b, nullptr, hb, nullptr, nullptr, 1024, 256);
  gemm128<3,2><<<1024, 256, 0, stream>>>(hb, wfc2T, fc2_b, x2n, out, nullptr, nullptr, 256, 1024);
}

// Round 3
// 526.734 us; speedup vs baseline: 1.6757x; 1.1138x over previous
//
#include <hip/hip_runtime.h>

typedef unsigned short u16;
typedef __attribute__((ext_vector_type(8))) short s16x8;   // 8 bf16 in 4 VGPRs
typedef __attribute__((ext_vector_type(4))) float f32x4;

#define MFMA_BF16(a,b,c) __builtin_amdgcn_mfma_f32_16x16x32_bf16((a),(b),(c),0,0,0)

// async global->LDS, 16B per lane. LDS dest is wave-uniform base + lane*16;
// our staging layouts are lane-linear so per-lane pointer == base + lane*16.
#define GLL(gp, lp) __builtin_amdgcn_global_load_lds( \
    (const __attribute__((address_space(1))) void*)(gp), \
    (__attribute__((address_space(3))) void*)(lp), 16, 0, 0)

// counted-vmcnt barrier: wait for all but the newest N vmem ops, then s_barrier.
// asm memory clobber + sched_barrier(0) fence per guide rule #18.
#define PIPE_WAIT_BAR(N) do { \
  asm volatile("s_waitcnt vmcnt(" #N ")" ::: "memory"); \
  __builtin_amdgcn_sched_barrier(0); \
  __builtin_amdgcn_s_barrier(); \
  __builtin_amdgcn_sched_barrier(0); \
} while (0)

#define PIPE_BAR() do { \
  asm volatile("" ::: "memory"); \
  __builtin_amdgcn_sched_barrier(0); \
  __builtin_amdgcn_s_barrier(); \
  __builtin_amdgcn_sched_barrier(0); \
} while (0)

__device__ __forceinline__ float b2f(u16 s){
  union { unsigned u; float f; } v; v.u = ((unsigned)s) << 16; return v.f;
}
__device__ __forceinline__ u16 f2b(float x){
  union { float f; unsigned u; } v; v.f = x;
  unsigned u = v.u;
  return (u16)((u + 0x7FFFu + ((u >> 16) & 1u)) >> 16);   // round-to-nearest-even
}
__device__ __forceinline__ u16 f2b_trunc(float x){
  union { float f; unsigned u; } v; v.f = x;
  return (u16)(v.u >> 16);                                 // truncate (softmax-safe)
}

// exact-enough GELU: erf via Abramowitz-Stegun 7.1.26 (max abs err 1.5e-7,
// far below bf16 ulp) — ~12 VALU ops vs libm erff's ~60+.
__device__ __forceinline__ float gelu_fast(float v){
  float av = fabsf(v) * 0.70710678118654752f;
  float t  = __builtin_amdgcn_rcpf(1.0f + 0.3275911f * av);
  float p  = ((((1.061405429f * t - 1.453152027f) * t + 1.421413741f) * t
               - 0.284496736f) * t + 0.254829592f) * t;
  float erfa = 1.0f - p * __expf(-av * av);
  return 0.5f * v * (1.0f + copysignf(erfa, v));
}

// ---------------- all weight converts in one dispatch (f32 [K][N] -> bf16 [N][K]) ----------------
__global__ __launch_bounds__(256) void wconv_all(
    const float* __restrict__ w0, u16* __restrict__ t0,   // qkv  256x768
    const float* __restrict__ w1, u16* __restrict__ t1,   // proj 256x256
    const float* __restrict__ w2, u16* __restrict__ t2,   // fc   256x1024
    const float* __restrict__ w3, u16* __restrict__ t3)   // fc2  1024x256
{
  int bid = blockIdx.x;
  const float* w; u16* t; int K, N, base;
  if (bid < 768)        { w = w0; t = t0; K = 256;  N = 768;  base = bid; }
  else if (bid < 1024)  { w = w1; t = t1; K = 256;  N = 256;  base = bid - 768; }
  else if (bid < 2048)  { w = w2; t = t2; K = 256;  N = 1024; base = bid - 1024; }
  else                  { w = w3; t = t3; K = 1024; N = 256;  base = bid - 2048; }
  int idx = base * 256 + threadIdx.x;
  if (idx >= K * N) return;
  int k = idx / N, n = idx - k * N;
  t[(size_t)n * K + k] = f2b(w[idx]);
}

// ---------------- LayerNorm over C=256, one wave per row; f32 in -> bf16 out ----------------
__global__ __launch_bounds__(256) void ln_f32(const float* __restrict__ in,
    const float* __restrict__ gam, const float* __restrict__ bet, u16* __restrict__ out)
{
  int wv = threadIdx.x >> 6, lane = threadIdx.x & 63;
  size_t row = (size_t)blockIdx.x * 4 + wv;
  float4 u = *(const float4*)(in + row * 256 + lane * 4);
  float s  = u.x + u.y + u.z + u.w;
  float s2 = u.x*u.x + u.y*u.y + u.z*u.z + u.w*u.w;
  #pragma unroll
  for (int off = 32; off; off >>= 1){
    s  += __shfl_xor(s, off);
    s2 += __shfl_xor(s2, off);
  }
  float mean = s * (1.0f/256.0f);
  float var  = s2 * (1.0f/256.0f) - mean*mean;
  float rs   = rsqrtf(var + 1e-5f);
  int c = lane * 4;
  float4 g4 = *(const float4*)(gam + c);
  float4 b4 = *(const float4*)(bet + c);
  ushort4 o;
  o.x = f2b((u.x - mean)*rs*g4.x + b4.x);
  o.y = f2b((u.y - mean)*rs*g4.y + b4.y);
  o.z = f2b((u.z - mean)*rs*g4.z + b4.z);
  o.w = f2b((u.w - mean)*rs*g4.w + b4.w);
  *(ushort4*)(out + row * 256 + c) = o;
}

// ---------------- 128x128-tile bf16 MFMA GEMM, XCD-swizzled 1D grid ----------------
// K-loop is a DEPTH-3 pipeline: global_load_lds (16B) into triple-buffered LDS.
// Loads are issued 3 K-steps ahead; in-loop wait is vmcnt(8) (two stages stay
// in flight across the barrier), tail peels with vmcnt(8)/(4)/(0). This hides
// ~2 K-steps (~600cy) of L2/HBM latency vs depth-1's ~150cy.
// Epilogue: LDS-staged chunks; readback stores full contiguous 128B lines.
// EPI 0: QKV scatter (+bias) -> o0=q (PRE-SCALED by 1/sqrt(32)), o1=k, o2=v, [bah][t][d] bf16
// EPI 2: fast GELU bf16      -> o0[row*N+col] = gelu(acc + bias)
// EPI 3: residual add f32    -> ((float*)o0)[row*N+col] = res + acc + bias
template<int EPI, int NT>
__global__ __launch_bounds__(256) void gemm128(
    const u16* __restrict__ A, const u16* __restrict__ Bt, const float* __restrict__ bias,
    const u16* __restrict__ res, void* __restrict__ o0v, u16* __restrict__ o1, u16* __restrict__ o2,
    int N, int K)
{
  // triple buffer: buf b at lds + b*8192 u16 (A 4096 | B 4096). 48KB total.
  // epilogue chunk reuses buffer 0 space (max 17024B needed).
  __shared__ __align__(16) u16 lds[24576];
  int tid = threadIdx.x;
  int w = tid >> 6, lane = tid & 63;
  int quad = lane >> 4, c = lane & 15;
  int bid = blockIdx.x;
  int x = bid & 7, j = bid >> 3;
  int nt = j % NT, mt = (j / NT) * 8 + x;
  int wm = (w >> 1) * 64, wn = (w & 1) * 64;
  const u16* Abase = A + (size_t)mt * 128 * K;
  const u16* Bbase = Bt + (size_t)nt * 128 * K;
  int m0 = tid & 127, jj0 = tid >> 7;   // chunk ci=tid -> (m0,jj0); ci=tid+256 -> (m0,jj0+2)
  f32x4 zero = {0.f, 0.f, 0.f, 0.f};
  f32x4 acc[4][4];
  #pragma unroll
  for (int mi = 0; mi < 4; mi++)
    #pragma unroll
    for (int ni = 0; ni < 4; ni++) acc[mi][ni] = zero;

  auto stage = [&](int buf, int k0){
    u16* base = &lds[buf * 8192];
    GLL(Abase + (size_t)m0 * K + k0 + jj0 * 8,       &base[tid * 8]);
    GLL(Abase + (size_t)m0 * K + k0 + (jj0 + 2) * 8, &base[2048 + tid * 8]);
    GLL(Bbase + (size_t)m0 * K + k0 + jj0 * 8,       &base[4096 + tid * 8]);
    GLL(Bbase + (size_t)m0 * K + k0 + (jj0 + 2) * 8, &base[6144 + tid * 8]);
  };
  auto compute = [&](int cb){
    const u16* Lb = &lds[cb * 8192];
    s16x8 af[4], bfr[4];
    #pragma unroll
    for (int mi = 0; mi < 4; mi++)
      af[mi] = *(const s16x8*)&Lb[(quad * 128 + wm + mi * 16 + c) * 8];
    #pragma unroll
    for (int ni = 0; ni < 4; ni++)
      bfr[ni] = *(const s16x8*)&Lb[4096 + (quad * 128 + wn + ni * 16 + c) * 8];
    #pragma unroll
    for (int mi = 0; mi < 4; mi++)
      #pragma unroll
      for (int ni = 0; ni < 4; ni++)
        acc[mi][ni] = MFMA_BF16(af[mi], bfr[ni], acc[mi][ni]);
  };

  // prologue: 3 stages in flight (K is always >= 96 here: 256 or 1024)
  stage(0, 0); stage(1, 32); stage(2, 64);
  int cur = 0;
  int k0 = 0;
  for (; k0 + 96 < K; k0 += 32){
    PIPE_WAIT_BAR(8);          // oldest stage (for this k-step) complete, all waves
    compute(cur);
    PIPE_BAR();                // all waves done reading buf[cur] before overwrite
    stage(cur, k0 + 96);       // refill 3 steps ahead
    cur = (cur == 2) ? 0 : cur + 1;
  }
  // tail: 3 staged steps remain, nothing more to stage
  PIPE_WAIT_BAR(8); compute(cur); cur = (cur == 2) ? 0 : cur + 1;
  PIPE_WAIT_BAR(4); compute(cur); cur = (cur == 2) ? 0 : cur + 1;
  PIPE_WAIT_BAR(0); compute(cur);

  // ---------------- LDS-staged coalesced epilogue ----------------
  // chunk ch covers tile rows [ch*32, ch*32+32). Staged by the two waves with
  // wm == (ch>>1)*64; read back by all 256 threads as full 128B lines.
  const int LS  = 132;                 // u16 chunk row stride
  const int LSF = 133;                 // f32 chunk row stride
  float* ldsF = (float*)lds;
  int rr = tid >> 3;                   // readback row within chunk [0,32)
  int c7 = tid & 7;

  #pragma unroll
  for (int ch = 0; ch < 4; ch++){
    __syncthreads();                   // prior reads of lds done
    if ((w >> 1) == (ch >> 1)){
      #pragma unroll
      for (int mi2 = 0; mi2 < 2; mi2++){
        int mi = (ch & 1) * 2 + mi2;
        #pragma unroll
        for (int ni = 0; ni < 4; ni++){
          int col = wn + ni * 16 + c;                    // tile-local col
          float bv = bias[nt * 128 + col];
          #pragma unroll
          for (int r = 0; r < 4; r++){
            int cr = mi2 * 16 + quad * 4 + r;            // chunk-local row
            float vv = acc[mi][ni][r] + bv;
            if (EPI == 0){
              int gcol = nt * 128 + col;
              if ((gcol >> 8) == 0) vv *= 0.17677669529663687f;   // q pre-scale
              lds[cr * LS + col] = f2b(vv);
            } else if (EPI == 2){
              lds[cr * LS + col] = f2b(gelu_fast(vv));
            } else {
              ldsF[cr * LSF + col] = vv;                 // residual added at readback
            }
          }
        }
      }
    }
    __syncthreads();
    int row = mt * 128 + ch * 32 + rr;                   // global output row
    if (EPI == 3){
      #pragma unroll
      for (int jj2 = 0; jj2 < 4; jj2++){
        int colL = c7 * 4 + jj2 * 32;                    // 8 lanes x 16B contiguous
        size_t gidx = (size_t)row * N + nt * 128 + colL;
        float4 vv = *(const float4*)&ldsF[rr * LSF + colL];
        ushort4 r4 = *(const ushort4*)(res + gidx);
        float4 o4;
        o4.x = vv.x + b2f(r4.x);
        o4.y = vv.y + b2f(r4.y);
        o4.z = vv.z + b2f(r4.z);
        o4.w = vv.w + b2f(r4.w);
        *(float4*)((float*)o0v + gidx) = o4;
      }
    } else {
      #pragma unroll
      for (int jj2 = 0; jj2 < 2; jj2++){
        int colL = c7 * 8 + jj2 * 64;                    // 8 lanes x 16B contiguous
        uint4 val = *(const uint4*)&lds[rr * LS + colL];
        if (EPI == 0){
          int gcol = nt * 128 + colL;
          int which = gcol >> 8, ccc = gcol & 255;
          int hh = ccc >> 5, d = ccc & 31;
          int ba = row >> 9, t = row & 511;
          size_t idx = (((size_t)(ba * 8 + hh)) * 512 + t) * 32 + d;
          u16* dst = (which == 0) ? (u16*)o0v : ((which == 1) ? o1 : o2);
          *(uint4*)(dst + idx) = val;
        } else {
          *(uint4*)((u16*)o0v + (size_t)row * N + nt * 128 + colL) = val;
        }
      }
    }
  }
}

// ---------------- fused proj GEMM + residual + LayerNorm2 -> x2n ----------------
// 2-phase global_load_lds pipeline (5 loads/stage -> vmcnt(5)).
// A=y [65536][256] bf16, Bt=projT [256][256], res=xn. Block = 64 rows x all 256 cols.
__global__ __launch_bounds__(256) void proj_ln(
    const u16* __restrict__ A, const u16* __restrict__ Bt, const float* __restrict__ bias,
    const u16* __restrict__ res, const float* __restrict__ gam, const float* __restrict__ bet,
    u16* __restrict__ x2n)
{
  // double buffer: buf b at lds + b*10240 u16 (A 2048 | B 8192). 40KB total.
  // epilogue x2 tile 64x264 u16 (33792B) reuses this space.
  __shared__ __align__(16) u16 lds[20480];
  int tid = threadIdx.x;
  int w = tid >> 6, lane = tid & 63;
  int quad = lane >> 4, c = lane & 15;
  int mt = blockIdx.x;                               // 64-row tiles
  int wn = w * 64;
  const u16* Abase = A + (size_t)mt * 64 * 256;
  int an = tid & 63, aj = tid >> 6;
  f32x4 zero = {0.f, 0.f, 0.f, 0.f};
  f32x4 acc[4][4];
  #pragma unroll
  for (int mi = 0; mi < 4; mi++)
    #pragma unroll
    for (int ni = 0; ni < 4; ni++) acc[mi][ni] = zero;

  auto stage = [&](int buf, int k0){
    u16* base = &lds[buf * 10240];
    GLL(Abase + (size_t)an * 256 + k0 + aj * 8, &base[tid * 8]);
    #pragma unroll
    for (int i = 0; i < 4; i++){
      int ci = tid + i * 256;
      int n = ci & 255, jjb = ci >> 8;
      GLL(Bt + (size_t)n * 256 + k0 + jjb * 8, &base[2048 + ci * 8]);
    }
  };
  auto compute = [&](int cb){
    const u16* base = &lds[cb * 10240];
    s16x8 af[4], bfr[4];
    #pragma unroll
    for (int mi = 0; mi < 4; mi++)
      af[mi] = *(const s16x8*)&base[(quad * 64 + mi * 16 + c) * 8];
    #pragma unroll
    for (int ni = 0; ni < 4; ni++)
      bfr[ni] = *(const s16x8*)&base[2048 + (quad * 256 + wn + ni * 16 + c) * 8];
    #pragma unroll
    for (int mi = 0; mi < 4; mi++)
      #pragma unroll
      for (int ni = 0; ni < 4; ni++)
        acc[mi][ni] = MFMA_BF16(af[mi], bfr[ni], acc[mi][ni]);
  };

  stage(0, 0);
  int cur = 0;
  for (int k0 = 32; k0 < 256; k0 += 32){
    stage(cur ^ 1, k0);
    PIPE_WAIT_BAR(5);
    compute(cur);
    PIPE_BAR();
    cur ^= 1;
  }
  PIPE_WAIT_BAR(0);
  compute(cur);
  __syncthreads();

  // epilogue: x2 = y@W + b + xn -> LDS tile [64][264] bf16
  #pragma unroll
  for (int ni = 0; ni < 4; ni++){
    int col = wn + ni * 16 + c;
    float bv = bias[col];
    #pragma unroll
    for (int mi = 0; mi < 4; mi++){
      #pragma unroll
      for (int r = 0; r < 4; r++){
        int rowL = mi * 16 + quad * 4 + r;
        size_t gidx = ((size_t)mt * 64 + rowL) * 256 + col;
        lds[rowL * 264 + col] = f2b(acc[mi][ni][r] + bv + b2f(res[gidx]));
      }
    }
  }
  __syncthreads();

  // LN pass: 4 threads per row, each owns 64 cols
  int rowL = tid >> 2, part = (tid & 3) * 64;
  float s = 0.f, s2 = 0.f;
  #pragma unroll
  for (int i = 0; i < 16; i++){
    ushort4 u = *(const ushort4*)&lds[rowL * 264 + part + i * 4];
    float v0 = b2f(u.x), v1 = b2f(u.y), v2 = b2f(u.z), v3 = b2f(u.w);
    s  += v0 + v1 + v2 + v3;
    s2 += v0*v0 + v1*v1 + v2*v2 + v3*v3;
  }
  s  += __shfl_xor(s, 1);  s  += __shfl_xor(s, 2);
  s2 += __shfl_xor(s2, 1); s2 += __shfl_xor(s2, 2);
  float mean = s * (1.0f/256.0f);
  float var  = s2 * (1.0f/256.0f) - mean*mean;
  float rs   = rsqrtf(var + 1e-5f);
  size_t orow = ((size_t)mt * 64 + rowL) * 256;
  #pragma unroll
  for (int i = 0; i < 16; i++){
    int col = part + i * 4;
    ushort4 u = *(const ushort4*)&lds[rowL * 264 + col];
    float4 g4 = *(const float4*)(gam + col);
    float4 b4 = *(const float4*)(bet + col);
    ushort4 o;
    o.x = f2b((b2f(u.x) - mean)*rs*g4.x + b4.x);
    o.y = f2b((b2f(u.y) - mean)*rs*g4.y + b4.y);
    o.z = f2b((b2f(u.z) - mean)*rs*g4.z + b4.z);
    o.w = f2b((b2f(u.w) - mean)*rs*g4.w + b4.w);
    *(ushort4*)(x2n + orow + col) = o;
  }
}

// ---------------- flash attention, no-max softmax; XCD-swizzled 1D grid ----------------
// q (pre-scaled), k, v: [bah][t][32] bf16; y: [ba][t][256] bf16.
// grid.x = 4096: x=bid&7, j=bid>>3: qt=j&3, bah=(j>>2)*8+x -> a bah's 4 q-tiles
// back-to-back on one XCD (K/V L2 reuse).
__global__ __launch_bounds__(256) void attn_kernel(const u16* __restrict__ q,
    const u16* __restrict__ k, const u16* __restrict__ v, u16* __restrict__ y)
{
  __shared__ __align__(16) u16 ldsK[32 * 36];    // [s][d], row stride 36
  __shared__ __align__(16) u16 ldsV[32 * 36];    // [d][s], row stride 36
  __shared__ __align__(16) u16 ldsp[4][16 * 36]; // per-wave P [prow][s], stride 36
  int tid = threadIdx.x;
  int w = tid >> 6, lane = tid & 63;
  int quad = lane >> 4, c = lane & 15;
  int bid = blockIdx.x;
  int x = bid & 7, j = bid >> 3;
  int qt = j & 3, bah = (j >> 2) * 8 + x;
  int q0 = qt * 128 + w * 32;
  const u16* qb = q + (size_t)bah * 16384;
  const u16* kb = k + (size_t)bah * 16384;
  const u16* vb = v + (size_t)bah * 16384;
  int krow = tid >> 3, kcol = (tid & 7) * 4;     // K staging: uint2 per thread
  int vd = tid & 31,  vs = (tid >> 5) * 4;       // V staging: 4 strided u16 -> b64

  s16x8 qf0 = *(const s16x8*)(qb + (q0 + c) * 32 + quad * 8);
  s16x8 qf1 = *(const s16x8*)(qb + (q0 + 16 + c) * 32 + quad * 8);
  float l0[4] = {0.f,0.f,0.f,0.f}, l1[4] = {0.f,0.f,0.f,0.f};
  f32x4 o00 = {0,0,0,0}, o01 = {0,0,0,0}, o10 = {0,0,0,0}, o11 = {0,0,0,0};
  f32x4 zero = {0,0,0,0};

  for (int s0 = 0; s0 < 512; s0 += 32){
    uint2 kr = *(const uint2*)(kb + (s0 + krow) * 32 + kcol);
    short4 vr;
    vr.x = (short)vb[(s0 + vs)     * 32 + vd];
    vr.y = (short)vb[(s0 + vs + 1) * 32 + vd];
    vr.z = (short)vb[(s0 + vs + 2) * 32 + vd];
    vr.w = (short)vb[(s0 + vs + 3) * 32 + vd];
    __syncthreads();
    *(uint2*)&ldsK[krow * 36 + kcol] = kr;
    *(short4*)&ldsV[vd * 36 + vs]   = vr;
    __syncthreads();

    s16x8 kf0 = *(const s16x8*)&ldsK[c * 36 + quad * 8];
    s16x8 kf1 = *(const s16x8*)&ldsK[(16 + c) * 36 + quad * 8];
    s16x8 vf0 = *(const s16x8*)&ldsV[c * 36 + quad * 8];
    s16x8 vf1 = *(const s16x8*)&ldsV[(16 + c) * 36 + quad * 8];

    f32x4 S0 = MFMA_BF16(qf0, kf0, zero);
    f32x4 S1 = MFMA_BF16(qf0, kf1, zero);
    #pragma unroll
    for (int r = 0; r < 4; r++){
      float p0 = __expf(S0[r]), p1 = __expf(S1[r]);
      l0[r] += p0 + p1;
      int prow = quad * 4 + r;
      ldsp[w][prow * 36 + c]      = f2b_trunc(p0);
      ldsp[w][prow * 36 + 16 + c] = f2b_trunc(p1);
    }
    s16x8 pf = *(const s16x8*)&ldsp[w][c * 36 + quad * 8];
    o00 = MFMA_BF16(pf, vf0, o00);
    o01 = MFMA_BF16(pf, vf1, o01);

    S0 = MFMA_BF16(qf1, kf0, zero);
    S1 = MFMA_BF16(qf1, kf1, zero);
    #pragma unroll
    for (int r = 0; r < 4; r++){
      float p0 = __expf(S0[r]), p1 = __expf(S1[r]);
      l1[r] += p0 + p1;
      int prow = quad * 4 + r;
      ldsp[w][prow * 36 + c]      = f2b_trunc(p0);
      ldsp[w][prow * 36 + 16 + c] = f2b_trunc(p1);
    }
    pf = *(const s16x8*)&ldsp[w][c * 36 + quad * 8];
    o10 = MFMA_BF16(pf, vf0, o10);
    o11 = MFMA_BF16(pf, vf1, o11);
  }

  #pragma unroll
  for (int r = 0; r < 4; r++){
    #pragma unroll
    for (int off = 8; off; off >>= 1){
      l0[r] += __shfl_xor(l0[r], off);
      l1[r] += __shfl_xor(l1[r], off);
    }
  }

  int ba = bah >> 3, hh = bah & 7;
  #pragma unroll
  for (int r = 0; r < 4; r++){
    int t0 = q0 + quad * 4 + r;
    float inv0 = 1.0f / l0[r], inv1 = 1.0f / l1[r];
    size_t base0 = ((size_t)(ba * 512 + t0)) * 256 + hh * 32;
    size_t base1 = base0 + 16 * 256;
    y[base0 + c]      = f2b(o00[r] * inv0);
    y[base0 + 16 + c] = f2b(o01[r] * inv0);
    y[base1 + c]      = f2b(o10[r] * inv1);
    y[base1 + 16 + c] = f2b(o11[r] * inv1);
  }
}

// ---------------- launch ----------------
extern "C" void kernel_launch(void* const* d_in, const int* in_sizes, int n_in,
                              void* d_out, int out_size, void* d_ws, size_t ws_size,
                              hipStream_t stream)
{
  const float* x      = (const float*)d_in[0];
  const float* ln1_w  = (const float*)d_in[1];
  const float* ln1_b  = (const float*)d_in[2];
  const float* qkv_w  = (const float*)d_in[3];
  const float* qkv_b  = (const float*)d_in[4];
  const float* proj_w = (const float*)d_in[5];
  const float* proj_b = (const float*)d_in[6];
  const float* ln2_w  = (const float*)d_in[7];
  const float* ln2_b  = (const float*)d_in[8];
  const float* fc_w   = (const float*)d_in[9];
  const float* fc_b   = (const float*)d_in[10];
  const float* fc2_w  = (const float*)d_in[11];
  const float* fc2_b  = (const float*)d_in[12];
  float* out = (float*)d_out;
  char* ws = (char*)d_ws;

  // ws layout (bytes) — compacted to cut poison-touch:
  // [0,32M) xn | [32M,166M) q|k|v|y (h overlaps) | [166M,200M) x2n | [200M,~201M) weights
  u16* xn   = (u16*)ws;
  u16* qb   = (u16*)(ws + (size_t)33554432);
  u16* kb   = qb + 16777216;
  u16* vb   = kb + 16777216;
  u16* yb   = vb + 16777216;
  u16* hb   = qb;                                   // overlap: q/k/v/y dead by FC1
  u16* x2n  = (u16*)(ws + (size_t)173015040);
  u16* wqkvT  = (u16*)(ws + (size_t)206569472);
  u16* wprojT = wqkvT + 196608;
  u16* wfcT   = wprojT + 65536;
  u16* wfc2T  = wfcT + 262144;

  wconv_all<<<3072, 256, 0, stream>>>(qkv_w, wqkvT, proj_w, wprojT, fc_w, wfcT, fc2_w, wfc2T);

  ln_f32<<<16384, 256, 0, stream>>>(x, ln1_w, ln1_b, xn);
  gemm128<0,6><<<3072, 256, 0, stream>>>(xn, wqkvT, qkv_b, nullptr, qb, kb, vb, 768, 256);
  attn_kernel<<<4096, 256, 0, stream>>>(qb, kb, vb, yb);
  proj_ln<<<1024, 256, 0, stream>>>(yb, wprojT, proj_b, xn, ln2_w, ln2_b, x2n);
  gemm128<2,8><<<4096, 256, 0, stream>>>(x2n, wfcT, fc_b, nullptr, hb, nullptr, nullptr, 1024, 256);
  gemm128<3,2><<<1024, 256, 0, stream>>>(hb, wfc2T, fc2_b, x2n, out, nullptr, nullptr, 256, 1024);
}